// Round 2
// 253.312 us; speedup vs baseline: 1.0516x; 1.0516x over previous
//
#include <hip/hip_runtime.h>

#define BATCH 8
#define INC 512
#define CM 512
#define CN 128
#define NPIX 4096
#define NSPLIT 8

typedef short bf16x8 __attribute__((ext_vector_type(8)));
typedef float f32x4 __attribute__((ext_vector_type(4)));
typedef unsigned short us8v __attribute__((ext_vector_type(8)));

__device__ __forceinline__ unsigned short f2b(float f) {
    union { float f; unsigned u; } v; v.f = f;
    unsigned r = v.u + 0x7FFF + ((v.u >> 16) & 1);
    return (unsigned short)(r >> 16);
}
__device__ __forceinline__ float b2f(unsigned short u) {
    union { unsigned u; float f; } v; v.u = ((unsigned)u) << 16;
    return v.f;
}

__device__ __forceinline__ void gl_lds16(const unsigned short* g, unsigned short* l) {
    __builtin_amdgcn_global_load_lds(
        (const __attribute__((address_space(1))) unsigned int*)g,
        (__attribute__((address_space(3))) unsigned int*)l, 16, 0, 0);
}

// Stage a [128 rows][32 bf16] tile (8KB) from row-major src (ld elems/row) at
// column kbase into LDS, 16B/lane, 2 issues/thread.
__device__ __forceinline__ void stage_tile(const unsigned short* src, int ld, int kbase,
                                           unsigned short* lds, int t) {
    #pragma unroll
    for (int q = 0; q < 2; ++q) {
        int f = q * 256 + t;
        const unsigned short* g = src + (size_t)(f >> 2) * ld + kbase + (f & 3) * 8;
        gl_lds16(g, lds + f * 8);
    }
}

// 4 waves, wave (wr,wc) owns 64x64; 16 MFMAs per BK=32 step.
__device__ __forceinline__ void bt_compute(const unsigned short* lA, const unsigned short* lB,
                                           f32x4 acc[4][4], int wr, int wc, int lane) {
    int lr = lane & 15, lq = lane >> 4;
    bf16x8 av[4], bv[4];
    #pragma unroll
    for (int i = 0; i < 4; ++i)
        av[i] = *(const bf16x8*)&lA[(wr * 64 + i * 16 + lr) * 32 + lq * 8];
    #pragma unroll
    for (int j = 0; j < 4; ++j)
        bv[j] = *(const bf16x8*)&lB[(wc * 64 + j * 16 + lr) * 32 + lq * 8];
    #pragma unroll
    for (int i = 0; i < 4; ++i)
        #pragma unroll
        for (int j = 0; j < 4; ++j)
            acc[i][j] = __builtin_amdgcn_mfma_f32_16x16x32_bf16(av[i], bv[j], acc[i][j], 0, 0, 0);
}

#define ZERO_ACC(acc)                       \
    f32x4 acc[4][4];                        \
    {                                       \
        f32x4 z4 = {0.f, 0.f, 0.f, 0.f};   \
        for (int i = 0; i < 4; ++i)         \
            for (int j = 0; j < 4; ++j)     \
                acc[i][j] = z4;             \
    }

// Double-buffered 1-deep pipelined K-loop: stage(t+1) issued before compute(t),
// ONE barrier per iter (syncthreads implies full vmcnt/lgkm drain). LDS layout:
// buf0 = [A 4096][B 4096] shorts, buf1 = +8192 shorts. Total 32KB.
__device__ __forceinline__ void pipe_loop(const unsigned short* A, int lda,
                                          const unsigned short* Bm, int ldb,
                                          int kbase, int nt,
                                          unsigned short* lds, f32x4 acc[4][4],
                                          int t, int wr, int wc, int lane)
{
    stage_tile(A, lda, kbase, lds, t);
    stage_tile(Bm, ldb, kbase, lds + 4096, t);
    __syncthreads();
    int cur = 0;
    for (int it = 0; it < nt - 1; ++it) {
        unsigned short* nb = lds + ((cur ^ 1) << 13);
        stage_tile(A, lda, kbase + (it + 1) * 32, nb, t);
        stage_tile(Bm, ldb, kbase + (it + 1) * 32, nb + 4096, t);
        bt_compute(lds + (cur << 13), lds + (cur << 13) + 4096, acc, wr, wc, lane);
        __syncthreads();
        cur ^= 1;
    }
    bt_compute(lds + (cur << 13), lds + (cur << 13) + 4096, acc, wr, wc, lane);
}

// K0: z<BATCH: xT16[b][n][c] + x16[b][c][n] from x. z==BATCH: weights fp32->bf16.
__global__ __launch_bounds__(256) void k_prep(
    const float* __restrict__ x, const float* __restrict__ wA,
    const float* __restrict__ wB, const float* __restrict__ wV,
    unsigned short* __restrict__ xT, unsigned short* __restrict__ x16,
    unsigned short* __restrict__ wA16, unsigned short* __restrict__ wB16,
    unsigned short* __restrict__ wV16)
{
    if (blockIdx.z == BATCH) {
        int bl = blockIdx.y * 64 + blockIdx.x;
        if (bl >= 384) return;
        int e = (bl * 256 + threadIdx.x) * 4;
        const float* src; unsigned short* dst; int off;
        if (e < 262144)       { src = wA; dst = wA16; off = e; }
        else if (e < 327680)  { src = wB; dst = wB16; off = e - 262144; }
        else                  { src = wV; dst = wV16; off = e - 327680; }
        float4 v = *(const float4*)&src[off];
        *(ushort4*)&dst[off] = make_ushort4(f2b(v.x), f2b(v.y), f2b(v.z), f2b(v.w));
        return;
    }
    __shared__ unsigned short tile[64][68];
    int n0 = blockIdx.x * 64, c0 = blockIdx.y * 64, b = blockIdx.z;
    int t = threadIdx.x;
    int tr = t >> 4, tc4 = (t & 15) * 4;
    const float* xb = x + ((size_t)b * INC + c0) * NPIX + n0;
    unsigned short* x16p = x16 + ((size_t)b * INC + c0) * NPIX + n0;
    #pragma unroll
    for (int p = 0; p < 4; ++p) {
        int r = p * 16 + tr;
        float4 v = *(const float4*)&xb[(size_t)r * NPIX + tc4];
        ushort4 u = make_ushort4(f2b(v.x), f2b(v.y), f2b(v.z), f2b(v.w));
        *(ushort4*)&x16p[(size_t)r * NPIX + tc4] = u;
        tile[r][tc4 + 0] = u.x; tile[r][tc4 + 1] = u.y;
        tile[r][tc4 + 2] = u.z; tile[r][tc4 + 3] = u.w;
    }
    __syncthreads();
    unsigned short* o = xT + ((size_t)b * NPIX + n0) * INC + c0;
    #pragma unroll
    for (int p = 0; p < 4; ++p) {
        int n = p * 16 + tr;
        ushort4 u = make_ushort4(tile[tc4 + 0][n], tile[tc4 + 1][n],
                                 tile[tc4 + 2][n], tile[tc4 + 3][n]);
        *(ushort4*)&o[(size_t)n * INC + tc4] = u;
    }
}

// K1: Bf16/V16 [b][k][n] = bf16(W @ x + bias).  grid (NPIX/128, B*2)
__global__ __launch_bounds__(256) void k_proj(
    const unsigned short* __restrict__ xT, const unsigned short* __restrict__ wB16,
    const unsigned short* __restrict__ wV16, const float* __restrict__ bB,
    const float* __restrict__ bV, unsigned short* __restrict__ Bf16,
    unsigned short* __restrict__ V16)
{
    __shared__ __align__(16) unsigned short lds[16384];
    int t = threadIdx.x;
    int n0 = blockIdx.x * 128;
    int z = blockIdx.y, b = z >> 1, br = z & 1;
    const unsigned short* A = br ? wV16 : wB16;
    const float* bias = br ? bV : bB;
    unsigned short* out = br ? V16 : Bf16;
    const unsigned short* Bm = xT + ((size_t)b * NPIX + n0) * INC;

    ZERO_ACC(acc);
    int lane = t & 63, w = t >> 6, wr = w >> 1, wc = w & 1;

    pipe_loop(A, INC, Bm, INC, 0, INC / 32, lds, acc, t, wr, wc, lane);

    // Direct epilogue: row k = wr*64+i*16+lq*4+reg, col n = n0+wc*64+j*16+lr
    int lr = lane & 15, lq = lane >> 4;
    int r0 = wr * 64 + lq * 4;
    unsigned short* op = out + (size_t)b * CN * NPIX + n0 + wc * 64 + lr;
    #pragma unroll
    for (int i = 0; i < 4; ++i)
        #pragma unroll
        for (int reg = 0; reg < 4; ++reg) {
            int k = r0 + i * 16 + reg;
            float bv_ = bias[k];
            #pragma unroll
            for (int j = 0; j < 4; ++j)
                op[(size_t)k * NPIX + j * 16] = f2b(acc[i][j][reg] + bv_);
        }
}

// K2: sB[b][k][n] = softmax over n.  grid (B*CN), 256 thr.
__global__ __launch_bounds__(256) void k_softmax_rows(
    const unsigned short* __restrict__ Bf16, unsigned short* __restrict__ sB)
{
    __shared__ float red[8];
    int row = blockIdx.x, t = threadIdx.x;
    const unsigned short* p = Bf16 + (size_t)row * NPIX + t * 16;
    us8v u0 = *(const us8v*)p, u1 = *(const us8v*)(p + 8);
    float v[16];
    #pragma unroll
    for (int j = 0; j < 8; ++j) { v[j] = b2f(u0[j]); v[8 + j] = b2f(u1[j]); }
    float m = -1e30f;
    #pragma unroll
    for (int j = 0; j < 16; ++j) m = fmaxf(m, v[j]);
    for (int o = 32; o > 0; o >>= 1) m = fmaxf(m, __shfl_xor(m, o));
    if ((t & 63) == 0) red[t >> 6] = m;
    __syncthreads();
    m = fmaxf(fmaxf(red[0], red[1]), fmaxf(red[2], red[3]));
    float s = 0.f;
    #pragma unroll
    for (int j = 0; j < 16; ++j) { v[j] = __expf(v[j] - m); s += v[j]; }
    for (int o = 32; o > 0; o >>= 1) s += __shfl_xor(s, o);
    if ((t & 63) == 0) red[4 + (t >> 6)] = s;
    __syncthreads();
    float r = 1.0f / (red[4] + red[5] + red[6] + red[7]);
    us8v o0, o1;
    #pragma unroll
    for (int j = 0; j < 8; ++j) { o0[j] = f2b(v[j] * r); o1[j] = f2b(v[8 + j] * r); }
    unsigned short* q = sB + (size_t)row * NPIX + t * 16;
    *(us8v*)q = o0; *(us8v*)(q + 8) = o1;
}

// K3: sVt[b][n][k] = softmax over k of V16[b][k][n], transposed. grid (NPIX/128, B)
__global__ __launch_bounds__(256) void k_softmax_cols(
    const unsigned short* __restrict__ V16, unsigned short* __restrict__ sVt)
{
    __shared__ unsigned short tv[128][138];
    __shared__ float pm[2][128], ps[2][128], sm[128], sr[128];
    int n0 = blockIdx.x * 128, b = blockIdx.y, t = threadIdx.x;
    const unsigned short* vb = V16 + (size_t)b * CN * NPIX + n0;
    #pragma unroll
    for (int it = 0; it < 8; ++it) {
        int f = it * 256 + t, k = f >> 4, n8 = (f & 15) * 8;
        us8v u = *(const us8v*)&vb[(size_t)k * NPIX + n8];
        #pragma unroll
        for (int j = 0; j < 8; ++j) tv[n8 + j][k] = u[j];
    }
    __syncthreads();
    {
        int p = t & 127, h = t >> 7;
        float m = -1e30f;
        for (int k = h * 64; k < h * 64 + 64; ++k) m = fmaxf(m, b2f(tv[p][k]));
        float s = 0.f;
        for (int k = h * 64; k < h * 64 + 64; ++k) s += __expf(b2f(tv[p][k]) - m);
        pm[h][p] = m; ps[h][p] = s;
    }
    __syncthreads();
    if (t < 128) {
        float ma = pm[0][t], mb = pm[1][t];
        float m = fmaxf(ma, mb);
        float s = ps[0][t] * __expf(ma - m) + ps[1][t] * __expf(mb - m);
        sm[t] = m; sr[t] = 1.0f / s;
    }
    __syncthreads();
    unsigned short* ob = sVt + ((size_t)b * NPIX + n0) * CN;
    #pragma unroll
    for (int it = 0; it < 8; ++it) {
        int idx = it * 2048 + t * 8, nl = idx >> 7, k0 = idx & 127;
        float m = sm[nl], r = sr[nl];
        us8v o;
        #pragma unroll
        for (int j = 0; j < 8; ++j) o[j] = f2b(__expf(b2f(tv[nl][k0 + j]) - m) * r);
        *(us8v*)&ob[(size_t)nl * CN + k0] = o;
    }
}

// K4: Pts[s][b][k][c] = sum_{n in split s} sB[k][n] * x16[c][n].  grid (INC/128, NSPLIT, B)
__global__ __launch_bounds__(256) void k_gather(
    const unsigned short* __restrict__ x16, const unsigned short* __restrict__ sB,
    float* __restrict__ Pts)
{
    __shared__ __align__(16) unsigned short lds[16384];
    int t = threadIdx.x;
    int c0 = blockIdx.x * 128, s = blockIdx.y, b = blockIdx.z;
    const unsigned short* A = sB + (size_t)b * CN * NPIX;
    const unsigned short* Bm = x16 + ((size_t)b * INC + c0) * NPIX;
    int nbase = s * (NPIX / NSPLIT);

    ZERO_ACC(acc);
    int lane = t & 63, w = t >> 6, wr = w >> 1, wc = w & 1;

    pipe_loop(A, NPIX, Bm, NPIX, nbase, (NPIX / NSPLIT) / 32, lds, acc, t, wr, wc, lane);

    int lr = lane & 15, lq = lane >> 4;
    int r0 = wr * 64 + lq * 4;
    float* op = Pts + ((size_t)s * BATCH + b) * CN * INC + c0 + wc * 64 + lr;
    #pragma unroll
    for (int i = 0; i < 4; ++i)
        #pragma unroll
        for (int reg = 0; reg < 4; ++reg) {
            int k = r0 + i * 16 + reg;
            #pragma unroll
            for (int j = 0; j < 4; ++j)
                op[(size_t)k * INC + j * 16] = acc[i][j][reg];
        }
}

// K5: Pt16[b][k][c] = bf16(sum_s Pts).  grid 512, 256 thr.
__global__ __launch_bounds__(256) void k_reduceP(
    const float* __restrict__ Pts, unsigned short* __restrict__ Pt16)
{
    int base = (blockIdx.x * 256 + threadIdx.x) * 4;
    float4 sacc = make_float4(0.f, 0.f, 0.f, 0.f);
    #pragma unroll
    for (int sp = 0; sp < NSPLIT; ++sp) {
        float4 v = *(const float4*)&Pts[(size_t)sp * (BATCH * CN * INC) + base];
        sacc.x += v.x; sacc.y += v.y; sacc.z += v.z; sacc.w += v.w;
    }
    *(ushort4*)&Pt16[base] = make_ushort4(f2b(sacc.x), f2b(sacc.y), f2b(sacc.z), f2b(sacc.w));
}

// K6: G16[b][m][k] = bf16(wA @ P + bA).  grid (CM/128, B)
__global__ __launch_bounds__(256) void k_G(
    const unsigned short* __restrict__ wA16, const float* __restrict__ bA,
    const unsigned short* __restrict__ Pt16, unsigned short* __restrict__ G16)
{
    __shared__ __align__(16) unsigned short lds[16384];
    int t = threadIdx.x;
    int m0 = blockIdx.x * 128, b = blockIdx.y;
    const unsigned short* A = wA16 + (size_t)m0 * INC;
    const unsigned short* Bm = Pt16 + (size_t)b * CN * INC;

    ZERO_ACC(acc);
    int lane = t & 63, w = t >> 6, wr = w >> 1, wc = w & 1;

    pipe_loop(A, INC, Bm, INC, 0, INC / 32, lds, acc, t, wr, wc, lane);

    int lr = lane & 15, lq = lane >> 4;
    int r0 = wr * 64 + lq * 4;
    unsigned short* op = G16 + ((size_t)b * CM + m0) * CN + wc * 64 + lr;
    #pragma unroll
    for (int i = 0; i < 4; ++i)
        #pragma unroll
        for (int reg = 0; reg < 4; ++reg) {
            int mloc = r0 + i * 16 + reg;
            float bv_ = bA[m0 + mloc];
            #pragma unroll
            for (int j = 0; j < 4; ++j)
                op[(size_t)mloc * CN + j * 16] = f2b(acc[i][j][reg] + bv_);
        }
}

// K7: out[b][m][n] = G @ sV + y.  grid (NPIX/128, CM/128, B)
__global__ __launch_bounds__(256) void k_Z(
    const unsigned short* __restrict__ G16, const unsigned short* __restrict__ sVt,
    const float* __restrict__ y, float* __restrict__ out)
{
    __shared__ __align__(16) unsigned short lds[16384];
    int t = threadIdx.x;
    int n0 = blockIdx.x * 128, m0 = blockIdx.y * 128, b = blockIdx.z;
    const unsigned short* A = G16 + ((size_t)b * CM + m0) * CN;
    const unsigned short* Bm = sVt + ((size_t)b * NPIX + n0) * CN;

    ZERO_ACC(acc);
    int lane = t & 63, w = t >> 6, wr = w >> 1, wc = w & 1;

    pipe_loop(A, CN, Bm, CN, 0, CN / 32, lds, acc, t, wr, wc, lane);

    // Direct epilogue with fused y-add: row m = m0+wr*64+i*16+lq*4+reg,
    // col n = n0+wc*64+j*16+lr. 64B segments per quarter-wave.
    int lr = lane & 15, lq = lane >> 4;
    size_t rbase = ((size_t)b * CM + m0 + wr * 64 + lq * 4) * NPIX + n0 + wc * 64 + lr;
    #pragma unroll
    for (int i = 0; i < 4; ++i)
        #pragma unroll
        for (int reg = 0; reg < 4; ++reg) {
            size_t ro = rbase + (size_t)(i * 16 + reg) * NPIX;
            #pragma unroll
            for (int j = 0; j < 4; ++j)
                out[ro + j * 16] = acc[i][j][reg] + y[ro + j * 16];
        }
}

extern "C" void kernel_launch(void* const* d_in, const int* in_sizes, int n_in,
                              void* d_out, int out_size, void* d_ws, size_t ws_size,
                              hipStream_t stream)
{
    const float* x  = (const float*)d_in[0];
    const float* y  = (const float*)d_in[1];
    const float* wA = (const float*)d_in[2];
    const float* bA = (const float*)d_in[3];
    const float* wB = (const float*)d_in[4];
    const float* bB = (const float*)d_in[5];
    const float* wV = (const float*)d_in[6];
    const float* bV = (const float*)d_in[7];
    float* out = (float*)d_out;

    unsigned short* xT16 = (unsigned short*)d_ws;            // 16,777,216
    unsigned short* x16  = xT16 + 16777216;                  // 16,777,216
    unsigned short* wA16 = x16  + 16777216;                  // 262,144
    unsigned short* wB16 = wA16 + 262144;                    // 65,536
    unsigned short* wV16 = wB16 + 65536;                     // 65,536
    unsigned short* Bf16 = wV16 + 65536;                     // 4,194,304
    unsigned short* V16  = Bf16 + 4194304;                   // 4,194,304
    unsigned short* sB   = V16  + 4194304;                   // 4,194,304
    unsigned short* sVt  = sB   + 4194304;                   // 4,194,304
    unsigned short* Pt16 = sVt  + 4194304;                   // 524,288
    float*  Pts = (float*)(Pt16 + 524288);                   // 8*8*128*512 f32
    unsigned short* G16  = (unsigned short*)(Pts + (size_t)NSPLIT * BATCH * CN * INC);

    k_prep<<<dim3(64, 8, BATCH + 1), 256, 0, stream>>>(
        x, wA, wB, wV, xT16, x16, wA16, wB16, wV16);
    k_proj<<<dim3(NPIX / 128, BATCH * 2), 256, 0, stream>>>(
        xT16, wB16, wV16, bB, bV, Bf16, V16);
    k_softmax_rows<<<dim3(BATCH * CN), 256, 0, stream>>>(Bf16, sB);
    k_softmax_cols<<<dim3(NPIX / 128, BATCH), 256, 0, stream>>>(V16, sVt);
    k_gather<<<dim3(INC / 128, NSPLIT, BATCH), 256, 0, stream>>>(x16, sB, Pts);
    k_reduceP<<<512, 256, 0, stream>>>(Pts, Pt16);
    k_G<<<dim3(CM / 128, BATCH), 256, 0, stream>>>(wA16, bA, Pt16, G16);
    k_Z<<<dim3(NPIX / 128, CM / 128, BATCH), 256, 0, stream>>>(G16, sVt, y, out);
}